// Round 1
// baseline (76.318 us; speedup 1.0000x reference)
//
#include <hip/hip_runtime.h>
#include <hip/hip_bf16.h>

// Problem: B=16, L=4096, H=256, fp32 in/out.
// out = x + T @ (x @ Wv^T @ Wo^T), T = causal uniform average.
// Reformulated: W = Wo@Wv; S = cumsum_L(x); out = x + (S @ W^T) * (1/(i+1)).

#define B_  16
#define L_  4096
#define H_  256
#define M_  (B_*L_)      // 65536 rows
#define K_  256
#define CH  64           // chunks per sequence
#define CHROWS (L_/CH)   // 64 rows per chunk

typedef short short8 __attribute__((ext_vector_type(8)));
typedef float f32x4  __attribute__((ext_vector_type(4)));

__device__ __forceinline__ unsigned short f2bf(float f) {
  unsigned int u = __builtin_bit_cast(unsigned int, f);
  u += 0x7fffu + ((u >> 16) & 1u);          // round-to-nearest-even
  return (unsigned short)(u >> 16);
}

__device__ __forceinline__ void gload_lds16(const void* g, void* l) {
  __builtin_amdgcn_global_load_lds(
      (const __attribute__((address_space(1))) unsigned int*)g,
      (__attribute__((address_space(3))) unsigned int*)l,
      16, 0, 0);
}

// ---------------- K1: W = Wo @ Wv -> bf16 row-major [H][H] ----------------
__global__ void fuse_w_kernel(const float* __restrict__ Wv,
                              const float* __restrict__ Wo,
                              unsigned short* __restrict__ Wbf) {
  __shared__ float wo[H_];
  int h = blockIdx.x, t = threadIdx.x;
  wo[t] = Wo[h*H_ + t];
  __syncthreads();
  float acc = 0.f;
  #pragma unroll 8
  for (int m = 0; m < H_; ++m) acc += wo[m] * Wv[m*H_ + t];
  Wbf[h*H_ + t] = f2bf(acc);
}

// ---------------- K2: per-chunk column sums of x ----------------
__global__ void partial_kernel(const float* __restrict__ x, float* __restrict__ P) {
  int c = blockIdx.x, b = blockIdx.y, t = threadIdx.x;
  const float* p = x + ((size_t)(b*L_ + c*CHROWS))*H_ + t;
  float s = 0.f;
  #pragma unroll 8
  for (int r = 0; r < CHROWS; ++r) s += p[(size_t)r*H_];
  P[(b*CH + c)*H_ + t] = s;
}

// ---------------- K3: exclusive scan of chunk sums (tiny) ----------------
__global__ void scan_kernel(const float* __restrict__ P, float* __restrict__ O) {
  int b = blockIdx.x, t = threadIdx.x;
  float run = 0.f;
  for (int c = 0; c < CH; ++c) {
    int idx = (b*CH + c)*H_ + t;
    O[idx] = run;
    run += P[idx];
  }
}

// ---------------- K4: S = inclusive cumsum(x) -> bf16 ----------------
__global__ void cumsum_kernel(const float* __restrict__ x, const float* __restrict__ O,
                              unsigned short* __restrict__ Sbf) {
  int c = blockIdx.x, b = blockIdx.y, t = threadIdx.x;
  size_t base = ((size_t)(b*L_ + c*CHROWS))*H_ + t;
  float run = O[(b*CH + c)*H_ + t];
  for (int r = 0; r < CHROWS; ++r) {
    run += x[base + (size_t)r*H_];
    Sbf[base + (size_t)r*H_] = f2bf(run);
  }
}

// ---------------- K5: out = x + (S @ W^T) / (i+1) ----------------
// m97-style: BM=BN=128, BK=64, 256 threads (4 waves, 2x2), global_load_lds w=16.
#define BM 128
#define BN 128
#define BK 64

__global__ __launch_bounds__(256, 2) void gemm_kernel(
    const unsigned short* __restrict__ Sbf,   // [M,K] bf16
    const unsigned short* __restrict__ Wbf,   // [N,K] bf16 (row-major = B^T layout)
    const float* __restrict__ x,
    float* __restrict__ out) {
  __shared__ __align__(16) unsigned short As[BM*BK];   // 16KB
  __shared__ __align__(16) unsigned short Bs[BN*BK];   // 16KB
  const int tid = threadIdx.x;
  const int rowBase = blockIdx.x * BM;
  const int colBase = blockIdx.y * BN;
  const int wave = tid >> 6, lane = tid & 63;
  const int wr = wave >> 1, wc = wave & 1;
  const int lrow = lane & 15;   // row within 16x16 fragment
  const int lk   = lane >> 4;   // k-group (8 elems each)

  f32x4 acc[4][4] = {};

  for (int t = 0; t < K_/BK; ++t) {
    const int k0 = t * BK;
    // stage A,B tiles: each 128 rows x 64 cols bf16 = 16KB = 4 iters x 256thr x 16B
    #pragma unroll
    for (int it = 0; it < 4; ++it) {
      int off = it*4096 + tid*16;          // linear byte offset in tile
      int r = off >> 7, cb = off & 127;    // tile row, col-byte (row = 128B)
      gload_lds16((const char*)Sbf + ((size_t)(rowBase + r))*512 + k0*2 + cb,
                  (char*)As + off);
      gload_lds16((const char*)Wbf + ((size_t)(colBase + r))*512 + k0*2 + cb,
                  (char*)Bs + off);
    }
    __syncthreads();
    #pragma unroll
    for (int ks = 0; ks < 2; ++ks) {       // two 32-wide k sub-steps
      short8 a[4], b[4];
      #pragma unroll
      for (int i = 0; i < 4; ++i) {
        int ar = wr*64 + i*16 + lrow;
        a[i] = *(const short8*)((const char*)As + ar*128 + ks*64 + lk*16);
        int br = wc*64 + i*16 + lrow;
        b[i] = *(const short8*)((const char*)Bs + br*128 + ks*64 + lk*16);
      }
      #pragma unroll
      for (int i = 0; i < 4; ++i)
        #pragma unroll
        for (int j = 0; j < 4; ++j)
          acc[i][j] = __builtin_amdgcn_mfma_f32_16x16x32_bf16(a[i], b[j], acc[i][j], 0, 0, 0);
    }
    __syncthreads();
  }

  // epilogue: out = x + acc * 1/(row_in_seq+1)
  #pragma unroll
  for (int i = 0; i < 4; ++i) {
    #pragma unroll
    for (int j4 = 0; j4 < 4; ++j4) {
      int row = rowBase + wr*64 + i*16 + lk*4 + j4;
      float scale = 1.0f / (float)((row & (L_-1)) + 1);
      size_t rb = (size_t)row * H_;
      #pragma unroll
      for (int n = 0; n < 4; ++n) {
        int col = colBase + wc*64 + n*16 + lrow;
        out[rb + col] = x[rb + col] + acc[i][n][j4] * scale;
      }
    }
  }
}

extern "C" void kernel_launch(void* const* d_in, const int* in_sizes, int n_in,
                              void* d_out, int out_size, void* d_ws, size_t ws_size,
                              hipStream_t stream) {
  const float* x  = (const float*)d_in[0];
  const float* Wv = (const float*)d_in[1];
  const float* Wo = (const float*)d_in[2];
  float* out = (float*)d_out;

  char* ws = (char*)d_ws;
  unsigned short* Sbf = (unsigned short*)ws;                          // 32MB
  unsigned short* Wbf = (unsigned short*)(ws + (size_t)M_*K_*2);      // 128KB
  float* P = (float*)(ws + (size_t)M_*K_*2 + (size_t)H_*H_*2);       // 1MB
  float* O = P + B_*CH*H_;                                            // 1MB

  hipLaunchKernelGGL(fuse_w_kernel,  dim3(H_),      dim3(H_), 0, stream, Wv, Wo, Wbf);
  hipLaunchKernelGGL(partial_kernel, dim3(CH, B_),  dim3(H_), 0, stream, x, P);
  hipLaunchKernelGGL(scan_kernel,    dim3(B_),      dim3(H_), 0, stream, P, O);
  hipLaunchKernelGGL(cumsum_kernel,  dim3(CH, B_),  dim3(H_), 0, stream, x, O, Sbf);
  hipLaunchKernelGGL(gemm_kernel,    dim3(M_/BM, H_/BN), dim3(256), 0, stream,
                     Sbf, Wbf, x, out);
}